// Round 1
// 632.546 us; speedup vs baseline: 1.1246x; 1.1246x over previous
//
#include <hip/hip_runtime.h>
#include <math.h>

// Problem constants
#define B_    8
#define NT_   1024
#define DIM_  768
#define H_    12
#define HD_   64
#define SCALE_ 0.125f
#define T_ELEMS 6291456UL   // B*NT*DIM

typedef _Float16 half8  __attribute__((ext_vector_type(8)));
typedef _Float16 half4v __attribute__((ext_vector_type(4)));
typedef float    floatx4 __attribute__((ext_vector_type(4)));

#if __has_builtin(__builtin_amdgcn_exp2f)
#define EXP2F(x) __builtin_amdgcn_exp2f(x)
#else
#define EXP2F(x) exp2f(x)
#endif

// async global->LDS, 16B per lane; LDS dest = wave-uniform base + lane*16
#define GLD16(gp, lp) __builtin_amdgcn_global_load_lds( \
    (const __attribute__((address_space(1))) unsigned int*)(gp), \
    (__attribute__((address_space(3))) unsigned int*)(lp), 16, 0, 0)

// ---------------------------------------------------------------- conversion
__global__ void cvt4(const float* __restrict__ in, _Float16* __restrict__ out,
                     int n4) {
  int i = blockIdx.x * 256 + threadIdx.x;
  if (i < n4) {
    float4 v = ((const float4*)in)[i];
    half4v h = { (_Float16)v.x, (_Float16)v.y, (_Float16)v.z, (_Float16)v.w };
    *(half4v*)(out + 4 * (size_t)i) = h;
  }
}

// ---------------------------------------------------------------- GEMM
// m97 structure: 128x128 tile, BK=32, 4 waves (2x2), each wave 64x64 = 4x4
// frags of 16x16x32. Linear LDS (global_load_lds requires it), width-16
// async staging. C[m][n] = sum_k A[m][k]*Bt[n][k] + bias[n].
// MODE 0: fused QKV — Bt has 3*768 rows (wq;wk;wv contiguous), output col
//         n selects buffer sel=n/768 (tiles never straddle: 768%128==0),
//         out fp16 at outh + sel*T_ELEMS. MODE 1: fp32 out single buffer.
template<int MODE>
__global__ __launch_bounds__(256) void gemm128(
    const _Float16* __restrict__ A, const _Float16* __restrict__ Bt,
    const float* __restrict__ b0_, const float* __restrict__ b1_,
    const float* __restrict__ b2_, _Float16* __restrict__ outh,
    float* __restrict__ outf, int K)
{
  __shared__ _Float16 As[128 * 32];
  __shared__ _Float16 Bs[128 * 32];
  const int t    = threadIdx.x;
  const int w    = t >> 6, lane = t & 63;
  const int quad = lane >> 4, l16 = lane & 15;
  const int wm   = (w >> 1) * 64, wn = (w & 1) * 64;
  const int m0   = blockIdx.x * 128, n0 = blockIdx.y * 128;

  // staging: thread t covers LDS bytes [t*16, t*16+16) = row t/4, halves (t&3)*8
  const _Float16* gA = A  + (size_t)(m0 + (t >> 2)) * K + (t & 3) * 8;
  const _Float16* gB = Bt + (size_t)(n0 + (t >> 2)) * K + (t & 3) * 8;
  _Float16* lA = As + w * 512;   // wave-uniform base (+ lane*8 halves implicit)
  _Float16* lB = Bs + w * 512;
  const size_t rowK = (size_t)64 * K;

  floatx4 acc[4][4] = {};

  for (int k0 = 0; k0 < K; k0 += 32) {
    __syncthreads();                    // prev iter ds_reads drained (lgkmcnt)
    GLD16(gA + k0,        lA);          // rows 0..63
    GLD16(gA + rowK + k0, lA + 2048);   // rows 64..127
    GLD16(gB + k0,        lB);
    GLD16(gB + rowK + k0, lB + 2048);
    __syncthreads();                    // vmcnt(0) drain -> tile ready

    half8 af[4], bf[4];
#pragma unroll
    for (int i = 0; i < 4; i++)
      af[i] = *(const half8*)(As + (wm + i * 16 + l16) * 32 + quad * 8);
#pragma unroll
    for (int j = 0; j < 4; j++)
      bf[j] = *(const half8*)(Bs + (wn + j * 16 + l16) * 32 + quad * 8);
#pragma unroll
    for (int i = 0; i < 4; i++)
#pragma unroll
      for (int j = 0; j < 4; j++)
        acc[i][j] = __builtin_amdgcn_mfma_f32_16x16x32_f16(af[i], bf[j],
                                                           acc[i][j], 0, 0, 0);
  }

  // C/D layout: row = quad*4 + reg, col = lane&15  [m89/m91]
  const int sel = (MODE == 0) ? (n0 / 768) : 0;
  const float* bb = (MODE == 0)
                      ? (sel == 0 ? b0_ : (sel == 1 ? b1_ : b2_))
                      : b0_;
#pragma unroll
  for (int j = 0; j < 4; j++) {
    const int col = n0 + wn + j * 16 + l16;
    const int cl  = col - sel * 768;
    const float bv = bb[cl];
#pragma unroll
    for (int i = 0; i < 4; i++)
#pragma unroll
      for (int r = 0; r < 4; r++) {
        const int row = m0 + wm + i * 16 + quad * 4 + r;
        const float v = acc[i][j][r] + bv;
        if (MODE == 0)
          outh[(size_t)sel * T_ELEMS + (size_t)row * 768 + cl] = (_Float16)v;
        else
          outf[(size_t)row * 768 + col] = v;
      }
  }
}

// ---------------------------------------------------------------- attention
// One block per (qtile=64 rows, h, b). 256 threads = 4 waves; wave w owns
// q-rows [w*16, w*16+16). Two-pass exact softmax in exp2 domain:
//   pass 1: streaming row-max m (raw scores) and row-sum l over 1024 keys
//   pass 2: recompute S, p = exp2(s*C2 - mb) with mb = m*C2 + log2(l)
//           -> write attn (fp32) and accumulate O += P @ V via MFMA.
// Q fragments are loop-invariant -> held in registers (no Qs LDS).
__global__ __launch_bounds__(256) void attn_kernel(
    const _Float16* __restrict__ Qh, const _Float16* __restrict__ Kh,
    const _Float16* __restrict__ Vh, float* __restrict__ attn_out,
    _Float16* __restrict__ Xh)
{
  __shared__ _Float16 Ks[64][72];
  __shared__ _Float16 Vt[64][72];  // transposed: [d][key]
  __shared__ _Float16 Ps[64][72];  // probs (A-layout source): [q_local][key]

  const int t    = threadIdx.x;
  const int w    = t >> 6, lane = t & 63;
  const int quad = lane >> 4, l16 = lane & 15;
  const int qt = blockIdx.x, h = blockIdx.y, b = blockIdx.z;
  const int q0 = qt * 64;

  const _Float16* Qb = Qh + ((size_t)b * NT_) * DIM_ + h * HD_;
  const _Float16* Kb = Kh + ((size_t)b * NT_) * DIM_ + h * HD_;
  const _Float16* Vb = Vh + ((size_t)b * NT_) * DIM_ + h * HD_;

  const int lrow = t >> 2;          // 0..63
  const int lcol = (t & 3) * 16;    // 0,16,32,48

  // Q fragment (A-operand): row = w*16 + l16, k = ks*32 + quad*8 + j
  half8 qf[2];
  {
    const _Float16* qr = Qb + (size_t)(q0 + w * 16 + l16) * DIM_ + quad * 8;
    qf[0] = *(const half8*)(qr);
    qf[1] = *(const half8*)(qr + 32);
  }

  const float C2 = 0.18033688011112042f;  // SCALE * log2(e)
  float m_run[4], l_run[4];
#pragma unroll
  for (int r = 0; r < 4; r++) { m_run[r] = -INFINITY; l_run[r] = 0.0f; }

  // ---------------- pass 1: row max (raw) / sum (exp2 domain)
  for (int kt = 0; kt < 16; kt++) {
    __syncthreads();
    *(uint4*)(&Ks[lrow][lcol])     = *(const uint4*)(Kb + (size_t)(kt * 64 + lrow) * DIM_ + lcol);
    *(uint4*)(&Ks[lrow][lcol + 8]) = *(const uint4*)(Kb + (size_t)(kt * 64 + lrow) * DIM_ + lcol + 8);
    __syncthreads();

    floatx4 s[4] = {};
#pragma unroll
    for (int ks = 0; ks < 2; ks++) {
#pragma unroll
      for (int j = 0; j < 4; j++) {
        half8 bk = *(const half8*)(&Ks[j * 16 + l16][ks * 32 + quad * 8]);
        s[j] = __builtin_amdgcn_mfma_f32_16x16x32_f16(qf[ks], bk, s[j], 0, 0, 0);
      }
    }
#pragma unroll
    for (int r = 0; r < 4; r++) {
      float tm = fmaxf(fmaxf(s[0][r], s[1][r]), fmaxf(s[2][r], s[3][r]));
      for (int off = 1; off < 16; off <<= 1)
        tm = fmaxf(tm, __shfl_xor(tm, off, 64));
      const float nm  = fmaxf(m_run[r], tm);
      const float nmc = nm * C2;
      float ts = EXP2F(fmaf(s[0][r], C2, -nmc)) + EXP2F(fmaf(s[1][r], C2, -nmc))
               + EXP2F(fmaf(s[2][r], C2, -nmc)) + EXP2F(fmaf(s[3][r], C2, -nmc));
      for (int off = 1; off < 16; off <<= 1)
        ts += __shfl_xor(ts, off, 64);
      l_run[r] = l_run[r] * EXP2F((m_run[r] - nm) * C2) + ts;
      m_run[r] = nm;
    }
  }

  float mb[4];
#pragma unroll
  for (int r = 0; r < 4; r++) mb[r] = m_run[r] * C2 + log2f(l_run[r]);

  // ---------------- pass 2: probs out + O = P @ V
  floatx4 oacc[4] = {};
  float* attn_b = attn_out + ((size_t)(b * H_ + h) * NT_ + q0) * NT_;

  for (int kt = 0; kt < 16; kt++) {
    __syncthreads();
    *(uint4*)(&Ks[lrow][lcol])     = *(const uint4*)(Kb + (size_t)(kt * 64 + lrow) * DIM_ + lcol);
    *(uint4*)(&Ks[lrow][lcol + 8]) = *(const uint4*)(Kb + (size_t)(kt * 64 + lrow) * DIM_ + lcol + 8);
    {
      alignas(16) _Float16 vh[16];
      *(uint4*)(vh)     = *(const uint4*)(Vb + (size_t)(kt * 64 + lrow) * DIM_ + lcol);
      *(uint4*)(vh + 8) = *(const uint4*)(Vb + (size_t)(kt * 64 + lrow) * DIM_ + lcol + 8);
#pragma unroll
      for (int c = 0; c < 16; c++) Vt[lcol + c][lrow] = vh[c];
    }
    __syncthreads();

    // recompute S (identical inputs to pass 1 -> consistent m,l)
    floatx4 s[4] = {};
#pragma unroll
    for (int ks = 0; ks < 2; ks++) {
#pragma unroll
      for (int j = 0; j < 4; j++) {
        half8 bk = *(const half8*)(&Ks[j * 16 + l16][ks * 32 + quad * 8]);
        s[j] = __builtin_amdgcn_mfma_f32_16x16x32_f16(qf[ks], bk, s[j], 0, 0, 0);
      }
    }

    // normalized prob in one fma+exp2; write attn, stage P for PV
#pragma unroll
    for (int j = 0; j < 4; j++)
#pragma unroll
      for (int r = 0; r < 4; r++) {
        const float p = EXP2F(fmaf(s[j][r], C2, -mb[r]));
        const int qr = w * 16 + quad * 4 + r;
        attn_b[(size_t)qr * NT_ + kt * 64 + j * 16 + l16] = p;
        Ps[qr][j * 16 + l16] = (_Float16)p;
      }
    // Ps rows [w*16, w*16+16) written AND read only by wave w -> no barrier
    // (per-wave in-order LDS + compiler lgkmcnt waits).

#pragma unroll
    for (int ks = 0; ks < 2; ks++) {
      half8 pa = *(const half8*)(&Ps[w * 16 + l16][ks * 32 + quad * 8]);
#pragma unroll
      for (int j2 = 0; j2 < 4; j2++) {
        half8 bv = *(const half8*)(&Vt[j2 * 16 + l16][ks * 32 + quad * 8]);
        oacc[j2] = __builtin_amdgcn_mfma_f32_16x16x32_f16(pa, bv, oacc[j2], 0, 0, 0);
      }
    }
  }

  // write X (fp16, [B,NT,DIM] with head offset) for the output projection
#pragma unroll
  for (int j2 = 0; j2 < 4; j2++)
#pragma unroll
    for (int r = 0; r < 4; r++) {
      const int qr = q0 + w * 16 + quad * 4 + r;
      Xh[((size_t)b * NT_ + qr) * DIM_ + h * HD_ + j2 * 16 + l16] = (_Float16)oacc[j2][r];
    }
}

// ---------------------------------------------------------------- launch
extern "C" void kernel_launch(void* const* d_in, const int* in_sizes, int n_in,
                              void* d_out, int out_size, void* d_ws, size_t ws_size,
                              hipStream_t stream) {
  const float* tfeat = (const float*)d_in[0];
  const float* wq    = (const float*)d_in[1];
  const float* bq    = (const float*)d_in[2];
  const float* wk    = (const float*)d_in[3];
  const float* bk    = (const float*)d_in[4];
  const float* wv    = (const float*)d_in[5];
  const float* bv    = (const float*)d_in[6];
  const float* wp    = (const float*)d_in[7];
  const float* bp    = (const float*)d_in[8];
  float* out = (float*)d_out;

  const size_t T = T_ELEMS;                   // 6,291,456
  const size_t W = (size_t)DIM_ * DIM_;       // 589,824

  _Float16* ws  = (_Float16*)d_ws;
  _Float16* tfh = ws;
  _Float16* wqh = ws + T;          // wq;wk;wv contiguous -> fused Bt (2304 rows)
  _Float16* wkh = ws + T + W;
  _Float16* wvh = ws + T + 2 * W;
  _Float16* wph = ws + T + 3 * W;
  _Float16* Qh  = ws + T + 4 * W;  // Q;K;V contiguous -> sel*T offset in epilogue
  _Float16* Kh  = Qh + T;
  _Float16* Vh  = Kh + T;
  _Float16* Xh  = Vh + T;

  cvt4<<<(int)(T / 4 / 256), 256, 0, stream>>>(tfeat, tfh, (int)(T / 4));
  cvt4<<<(int)(W / 4 / 256), 256, 0, stream>>>(wq, wqh, (int)(W / 4));
  cvt4<<<(int)(W / 4 / 256), 256, 0, stream>>>(wk, wkh, (int)(W / 4));
  cvt4<<<(int)(W / 4 / 256), 256, 0, stream>>>(wv, wvh, (int)(W / 4));
  cvt4<<<(int)(W / 4 / 256), 256, 0, stream>>>(wp, wph, (int)(W / 4));

  // fused QKV: M=8192, N=3*768=2304, K=768
  gemm128<0><<<dim3(64, 18), 256, 0, stream>>>(tfh, wqh, bq, bk, bv, Qh, nullptr, 768);

  attn_kernel<<<dim3(NT_ / 64, H_, B_), 256, 0, stream>>>(Qh, Kh, Vh, out + T, Xh);

  // projection: M=8192, N=768, K=768, fp32 out
  gemm128<1><<<dim3(64, 6), 256, 0, stream>>>(Xh, wph, bp, nullptr, nullptr, nullptr, out, 768);
}